// Round 5
// baseline (638.805 us; speedup 1.0000x reference)
//
#include <hip/hip_runtime.h>

#define NUM_EDGES 262144
#define CARD 50000
#define EMB 128
#define EDGE_DIM 27

// ---------------------------------------------------------------------------
// Prep kernel: fold msg-path weights.
//   ws[0..26] = w2[j] = sum_k out_w[k] * edge_w[k,j]
//   ws[27]    = b2    = sum_k edge_b[k] * out_w[k] + out_b
// ---------------------------------------------------------------------------
__global__ void prep_kernel(const float* __restrict__ edge_w,
                            const float* __restrict__ edge_b,
                            const float* __restrict__ out_w,
                            const float* __restrict__ out_b,
                            float* __restrict__ ws) {
    int j = threadIdx.x;
    if (j < EDGE_DIM) {
        float s = 0.f;
        for (int k = 0; k < EMB; ++k) s += out_w[k] * edge_w[k * EDGE_DIM + j];
        ws[j] = s;
    } else if (j == EDGE_DIM) {
        float s = out_b[0];
        for (int k = 0; k < EMB; ++k) s += edge_b[k] * out_w[k];
        ws[EDGE_DIM] = s;
    }
}

// ---------------------------------------------------------------------------
// Main kernel: ONE edge per wave, 4 waves/block.
//  - Wave-uniform edge id -> index path on the scalar pipe.
//  - All 15 embedding-row gathers staged into LDS via global_load_lds
//    (dwordx4): 2 rows per instruction (lanes 0-31 row A, 32-63 row B),
//    8 instructions, ZERO result VGPRs -> the scheduler cannot serialize
//    them (R2-R4 failure mode: one-at-a-time gathers, ~21k cy/wave).
//  - Single vmcnt drain, then ds_read_b64 + FMAs. LDS slots are
//    wave-private: no __syncthreads anywhere.
//  - t==1 padding slots alias the node's real feat row (L1 hit), weight 0.
// ---------------------------------------------------------------------------
__global__ __launch_bounds__(256) void edge_pred_kernel(
    const int* __restrict__ x, const int* __restrict__ src,
    const int* __restrict__ dst, const int* __restrict__ neg_dst,
    const float* __restrict__ msg, const float* __restrict__ emb_type,
    const float* __restrict__ emb_feats, const float* __restrict__ out_w,
    const float* __restrict__ ws, float* __restrict__ out) {
    __shared__ float lds[4 * 16 * EMB];  // 4 waves x 16 slots x 512 B = 32 KB

    const int lane = threadIdx.x & 63;
    const int wave = threadIdx.x >> 6;
    const int e = __builtin_amdgcn_readfirstlane(blockIdx.x * 4 + wave);
    const int half = lane >> 5;   // 0: slot 2k, 1: slot 2k+1
    const int hl = lane & 31;     // 16B chunk index within a row

    // ---- msg term (independent, non-temporal, issued early) ----
    float mterm = 0.f;
    if (lane < EDGE_DIM)
        mterm = __builtin_nontemporal_load(msg + (size_t)e * EDGE_DIM + lane) * ws[lane];

    // ---- scalar index path ----
    const int n0 = src[e], n1 = dst[e], n2 = neg_dst[e];

    const float* rb[16];
    float wpad[3];
#pragma unroll
    for (int n = 0; n < 3; ++n) {
        const int node = (n == 0) ? n0 : (n == 1) ? n1 : n2;
        const int* xr = x + (size_t)node * 10;
        const int t = xr[0];
        const int c1 = xr[1], c2 = xr[2], c3 = xr[3], c4 = xr[4], c5 = xr[5],
                  c6 = xr[6], c7 = xr[7], c8 = xr[8], c9 = xr[9];
        const int i0 = (t == 0) ? c1 : (t == 1) ? c5 : c6;
        const int i1 = (t == 0) ? c2 : (t == 1) ? c5 : c7;
        const int i2 = (t == 0) ? c3 : (t == 1) ? c5 : c8;
        const int i3 = (t == 0) ? c4 : (t == 1) ? c5 : c9;
        const int h0 = (t == 0) ? 0 : (t == 1) ? 4 : 5;
        const int h1 = (t == 0) ? 1 : (t == 1) ? 4 : 6;
        const int h2 = (t == 0) ? 2 : (t == 1) ? 4 : 7;
        const int h3 = (t == 0) ? 3 : (t == 1) ? 4 : 8;
        wpad[n] = (t == 1) ? 0.f : 1.f;

        rb[5 * n + 0] = emb_type + (size_t)t * EMB;
        rb[5 * n + 1] = emb_feats + ((size_t)h0 * CARD + (size_t)i0) * EMB;
        rb[5 * n + 2] = emb_feats + ((size_t)h1 * CARD + (size_t)i1) * EMB;
        rb[5 * n + 3] = emb_feats + ((size_t)h2 * CARD + (size_t)i2) * EMB;
        rb[5 * n + 4] = emb_feats + ((size_t)h3 * CARD + (size_t)i3) * EMB;
    }
    rb[15] = emb_type;  // dummy slot (always cache-hot), never read back

    // ---- stage all 16 rows into LDS: 8 fire-and-forget lds-DMA loads ----
    float* wbase = lds + wave * (16 * EMB);
#pragma unroll
    for (int k = 0; k < 8; ++k) {
        const float* ga = rb[2 * k];
        const float* gb = rb[2 * k + 1];
        const float* g = (half ? gb : ga) + hl * 4;  // 16 B per lane
        __builtin_amdgcn_global_load_lds(
            (const __attribute__((address_space(1))) void*)g,
            (__attribute__((address_space(3))) void*)(wbase + k * 2 * EMB),
            16, 0, 0);
    }

    // single drain for ALL outstanding loads (per-wave, not a barrier)
    __builtin_amdgcn_s_waitcnt(0);

    // ---- accumulate from LDS ----
    const float2* rows = (const float2*)wbase;  // slot s: rows[s*64 + lane]
    float hx[3], hy[3];
#pragma unroll
    for (int n = 0; n < 3; ++n) {
        const float2 a0 = rows[(5 * n + 0) * 64 + lane];
        const float2 a1 = rows[(5 * n + 1) * 64 + lane];
        const float2 a2 = rows[(5 * n + 2) * 64 + lane];
        const float2 a3 = rows[(5 * n + 3) * 64 + lane];
        const float2 a4 = rows[(5 * n + 4) * 64 + lane];
        const float bx = a2.x + a3.x + a4.x;
        const float by = a2.y + a3.y + a4.y;
        hx[n] = a0.x + a1.x + wpad[n] * bx;
        hy[n] = a0.y + a1.y + wpad[n] * by;
    }

    const float2 wv = *(const float2*)(out_w + lane * 2);
    float p = fmaxf(hx[0] + hx[1], 0.f) * wv.x + fmaxf(hy[0] + hy[1], 0.f) * wv.y + mterm;
    float q = fmaxf(hx[0] + hx[2], 0.f) * wv.x + fmaxf(hy[0] + hy[2], 0.f) * wv.y + mterm;

#pragma unroll
    for (int off = 32; off > 0; off >>= 1) {
        p += __shfl_xor(p, off, 64);
        q += __shfl_xor(q, off, 64);
    }

    if (lane == 0) {
        const float b2 = ws[EDGE_DIM];
        out[e] = p + b2;
        out[NUM_EDGES + e] = q + b2;
    }
}

extern "C" void kernel_launch(void* const* d_in, const int* in_sizes, int n_in,
                              void* d_out, int out_size, void* d_ws, size_t ws_size,
                              hipStream_t stream) {
    const int* x = (const int*)d_in[0];
    const int* src = (const int*)d_in[1];
    const int* dst = (const int*)d_in[2];
    const int* neg_dst = (const int*)d_in[3];
    const float* msg = (const float*)d_in[4];
    const float* emb_type = (const float*)d_in[5];
    const float* emb_feats = (const float*)d_in[6];
    const float* edge_w = (const float*)d_in[7];
    const float* edge_b = (const float*)d_in[8];
    const float* out_w = (const float*)d_in[9];
    const float* out_b = (const float*)d_in[10];
    float* out = (float*)d_out;
    float* ws = (float*)d_ws;

    prep_kernel<<<1, 64, 0, stream>>>(edge_w, edge_b, out_w, out_b, ws);

    const int blocks = NUM_EDGES / 4;  // 4 waves/block, 1 edge/wave
    edge_pred_kernel<<<blocks, 256, 0, stream>>>(x, src, dst, neg_dst, msg,
                                                 emb_type, emb_feats, out_w, ws,
                                                 out);
}

// Round 6
// 547.594 us; speedup vs baseline: 1.1666x; 1.1666x over previous
//
#include <hip/hip_runtime.h>

#define NUM_EDGES 262144
#define CARD 50000
#define EMB 128
#define EDGE_DIM 27

// ---------------------------------------------------------------------------
// Prep kernel: fold msg-path weights.
//   ws[0..26] = w2[j] = sum_k out_w[k] * edge_w[k,j]
//   ws[27]    = b2    = sum_k edge_b[k] * out_w[k] + out_b
// ---------------------------------------------------------------------------
__global__ void prep_kernel(const float* __restrict__ edge_w,
                            const float* __restrict__ edge_b,
                            const float* __restrict__ out_w,
                            const float* __restrict__ out_b,
                            float* __restrict__ ws) {
    int j = threadIdx.x;
    if (j < EDGE_DIM) {
        float s = 0.f;
        for (int k = 0; k < EMB; ++k) s += out_w[k] * edge_w[k * EDGE_DIM + j];
        ws[j] = s;
    } else if (j == EDGE_DIM) {
        float s = out_b[0];
        for (int k = 0; k < EMB; ++k) s += edge_b[k] * out_w[k];
        ws[EDGE_DIM] = s;
    }
}

// ---------------------------------------------------------------------------
// Main kernel: ONE edge per wave, 4 waves/block, NO LDS.
//  - R2-R5 post-mortem: every compiler-mediated gather path (VGPR loads,
//    sched_barrier, lds-DMA) ends up with ~1 outstanding gather/wave
//    (~700-900 cy each, serialized). So the 15 row-gathers are issued as
//    ORDERED VOLATILE INLINE ASM with forced distinct result VGPRs and a
//    single s_waitcnt vmcnt(0) that ties through all results. The compiler
//    cannot re-serialize or insert intermediate waits.
//  - Wave-uniform edge id -> index path on the scalar pipe; gather address
//    = SGPR base pair + shared lane*8 voffset VGPR.
//  - t==1 padding gathers alias the node's real feat row (cache hit), w=0.
// ---------------------------------------------------------------------------
__global__ __launch_bounds__(256) void edge_pred_kernel(
    const int* __restrict__ x, const int* __restrict__ src,
    const int* __restrict__ dst, const int* __restrict__ neg_dst,
    const float* __restrict__ msg, const float* __restrict__ emb_type,
    const float* __restrict__ emb_feats, const float* __restrict__ out_w,
    const float* __restrict__ ws, float* __restrict__ out) {
    const int lane = threadIdx.x & 63;
    const int wave = threadIdx.x >> 6;
    const int e = __builtin_amdgcn_readfirstlane(blockIdx.x * 4 + wave);

    // ---- msg term (independent; drained by our vmcnt(0) too) ----
    float mterm = 0.f;
    if (lane < EDGE_DIM)
        mterm = __builtin_nontemporal_load(msg + (size_t)e * EDGE_DIM + lane) * ws[lane];

    // ---- scalar index path (wave-uniform -> s_load) ----
    const int n0 = __builtin_amdgcn_readfirstlane(src[e]);
    const int n1 = __builtin_amdgcn_readfirstlane(dst[e]);
    const int n2 = __builtin_amdgcn_readfirstlane(neg_dst[e]);

    const float* rb[15];
    float wpad[3];
#pragma unroll
    for (int n = 0; n < 3; ++n) {
        const int node = (n == 0) ? n0 : (n == 1) ? n1 : n2;
        const int* xr = x + (size_t)node * 10;
        const int t = xr[0];
        const int c1 = xr[1], c2 = xr[2], c3 = xr[3], c4 = xr[4], c5 = xr[5],
                  c6 = xr[6], c7 = xr[7], c8 = xr[8], c9 = xr[9];
        const int i0 = (t == 0) ? c1 : (t == 1) ? c5 : c6;
        const int i1 = (t == 0) ? c2 : (t == 1) ? c5 : c7;
        const int i2 = (t == 0) ? c3 : (t == 1) ? c5 : c8;
        const int i3 = (t == 0) ? c4 : (t == 1) ? c5 : c9;
        const int h0 = (t == 0) ? 0 : (t == 1) ? 4 : 5;
        const int h1 = (t == 0) ? 1 : (t == 1) ? 4 : 6;
        const int h2 = (t == 0) ? 2 : (t == 1) ? 4 : 7;
        const int h3 = (t == 0) ? 3 : (t == 1) ? 4 : 8;
        wpad[n] = (t == 1) ? 0.f : 1.f;

        rb[5 * n + 0] = emb_type + (size_t)t * EMB;
        rb[5 * n + 1] = emb_feats + ((size_t)h0 * CARD + (size_t)i0) * EMB;
        rb[5 * n + 2] = emb_feats + ((size_t)h1 * CARD + (size_t)i1) * EMB;
        rb[5 * n + 3] = emb_feats + ((size_t)h2 * CARD + (size_t)i2) * EMB;
        rb[5 * n + 4] = emb_feats + ((size_t)h3 * CARD + (size_t)i3) * EMB;
    }

    // ---- 15 ordered fire-and-forget gathers, forced distinct result VGPRs --
    const unsigned voff = (unsigned)lane * 8u;  // 8 B per lane within a row
    float2 r0, r1, r2, r3, r4, r5, r6, r7, r8, r9, r10, r11, r12, r13, r14;
#define GLD(reg, idx)                                                       \
    asm volatile("global_load_dwordx2 %0, %1, %2"                           \
                 : "=&v"(reg)                                               \
                 : "v"(voff), "s"(rb[idx]))
    GLD(r0, 0);  GLD(r1, 1);  GLD(r2, 2);  GLD(r3, 3);  GLD(r4, 4);
    GLD(r5, 5);  GLD(r6, 6);  GLD(r7, 7);  GLD(r8, 8);  GLD(r9, 9);
    GLD(r10, 10); GLD(r11, 11); GLD(r12, 12); GLD(r13, 13); GLD(r14, 14);
#undef GLD

    // single drain; ties through every result so no consumer floats above it
    asm volatile("s_waitcnt vmcnt(0)"
                 : "+v"(r0), "+v"(r1), "+v"(r2), "+v"(r3), "+v"(r4),
                   "+v"(r5), "+v"(r6), "+v"(r7), "+v"(r8), "+v"(r9),
                   "+v"(r10), "+v"(r11), "+v"(r12), "+v"(r13), "+v"(r14)
                 :
                 : "memory");

    // ---- accumulate ----
    const float hx0 = r0.x + r1.x + wpad[0] * (r2.x + r3.x + r4.x);
    const float hy0 = r0.y + r1.y + wpad[0] * (r2.y + r3.y + r4.y);
    const float hx1 = r5.x + r6.x + wpad[1] * (r7.x + r8.x + r9.x);
    const float hy1 = r5.y + r6.y + wpad[1] * (r7.y + r8.y + r9.y);
    const float hx2 = r10.x + r11.x + wpad[2] * (r12.x + r13.x + r14.x);
    const float hy2 = r10.y + r11.y + wpad[2] * (r12.y + r13.y + r14.y);

    const float2 wv = *(const float2*)(out_w + lane * 2);
    float p = fmaxf(hx0 + hx1, 0.f) * wv.x + fmaxf(hy0 + hy1, 0.f) * wv.y + mterm;
    float q = fmaxf(hx0 + hx2, 0.f) * wv.x + fmaxf(hy0 + hy2, 0.f) * wv.y + mterm;

#pragma unroll
    for (int off = 32; off > 0; off >>= 1) {
        p += __shfl_xor(p, off, 64);
        q += __shfl_xor(q, off, 64);
    }

    if (lane == 0) {
        const float b2 = ws[EDGE_DIM];
        out[e] = p + b2;
        out[NUM_EDGES + e] = q + b2;
    }
}

extern "C" void kernel_launch(void* const* d_in, const int* in_sizes, int n_in,
                              void* d_out, int out_size, void* d_ws, size_t ws_size,
                              hipStream_t stream) {
    const int* x = (const int*)d_in[0];
    const int* src = (const int*)d_in[1];
    const int* dst = (const int*)d_in[2];
    const int* neg_dst = (const int*)d_in[3];
    const float* msg = (const float*)d_in[4];
    const float* emb_type = (const float*)d_in[5];
    const float* emb_feats = (const float*)d_in[6];
    const float* edge_w = (const float*)d_in[7];
    const float* edge_b = (const float*)d_in[8];
    const float* out_w = (const float*)d_in[9];
    const float* out_b = (const float*)d_in[10];
    float* out = (float*)d_out;
    float* ws = (float*)d_ws;

    prep_kernel<<<1, 64, 0, stream>>>(edge_w, edge_b, out_w, out_b, ws);

    const int blocks = NUM_EDGES / 4;  // 4 waves/block, 1 edge/wave
    edge_pred_kernel<<<blocks, 256, 0, stream>>>(x, src, dst, neg_dst, msg,
                                                 emb_type, emb_feats, out_w, ws,
                                                 out);
}